// Round 5
// baseline (102.663 us; speedup 1.0000x reference)
//
#include <hip/hip_runtime.h>
#include <hip/hip_bf16.h>

// Problem constants (B=4, L=4096, C=512, H=16, Dh=32, K=13)
#define BATCH   4
#define LSEQ    4096
#define CCH     512
#define HNUM    16
#define DH      32
#define KSZ     13
#define NHALF   6           // K/2
#define M_TOT   16384       // B*L
#define N_QKV   1536        // 3*C
#define KDIM    512         // C
#define BKQ     32          // K-step (16 tiles); subtile = 16 rows x 32 cols = 1KB

typedef __attribute__((ext_vector_type(8))) short  short8;
typedef __attribute__((ext_vector_type(4))) short  short4_t;
typedef __attribute__((ext_vector_type(4))) float  float4_t;

__device__ __forceinline__ unsigned short f32_to_bf16(float f) {
    union { float f; unsigned int u; } un; un.f = f;
    unsigned int u = un.u;
    u += 0x7FFFu + ((u >> 16) & 1u);   // RNE (inputs are finite)
    return (unsigned short)(u >> 16);
}
__device__ __forceinline__ float bf16_to_f32(unsigned short h) {
    union { unsigned int u; float f; } un; un.u = ((unsigned int)h) << 16;
    return un.f;
}

// async global(16B/lane) -> LDS; lds base must be wave-uniform, HW adds lane*16
__device__ __forceinline__ void gload_lds16(const unsigned short* g, unsigned short* l) {
    __builtin_amdgcn_global_load_lds(
        (const __attribute__((address_space(1))) unsigned int*)g,
        (__attribute__((address_space(3))) unsigned int*)l,
        16, 0, 0);
}

// ---------------------------------------------------------------- cvt f32->bf16
__global__ void cvt_f32_bf16_v4(const float4_t* __restrict__ in,
                                short4_t* __restrict__ out, int n4) {
    int i = blockIdx.x * blockDim.x + threadIdx.x;
    int stride = gridDim.x * blockDim.x;
    for (; i < n4; i += stride) {
        float4_t v = in[i];
        short4_t h;
        h.x = (short)f32_to_bf16(v.x);
        h.y = (short)f32_to_bf16(v.y);
        h.z = (short)f32_to_bf16(v.z);
        h.w = (short)f32_to_bf16(v.w);
        out[i] = h;
    }
}

// ---------------------------------------------------------------- GEMM 1: QKV
// Xb (bf16, 16384x512) @ W^T (bf16 1536x512) + bias -> qkv bf16 (3,B,H,L,Dh)
// BM=BN=256, BK=32, 8 waves (2M x 4N, wave-tile 128x64).
// LDS subtiled: subtile s = 16 rows x 32 cols stored contiguously (1KB);
//   gload_lds lane ln -> (row s*16+(ln&15), elems (ln>>4)*8)  == linear dest.
//   Fragment read = 1KB contiguous ds_read_b128 per subtile -> 0 conflicts.
// Triple buffer, prefetch distance 2, single barrier + vmcnt(4) per K-tile.
__global__ __launch_bounds__(512, 1) void gemm_qkv(
    const unsigned short* __restrict__ Xb,
    const unsigned short* __restrict__ W,
    const float* __restrict__ bias,
    unsigned short* __restrict__ qkvout)
{
    extern __shared__ __align__(16) unsigned short lds[];  // 3 * 32KB
    const int tid  = threadIdx.x;
    const int wv   = tid >> 6, ln = tid & 63;

    const int wg   = blockIdx.x;
    const int swz  = (wg & 7) * 48 + (wg >> 3);   // bijective (384 = 8*48)
    const int m0   = (swz & 63) * 256;            // 64 M-tiles
    const int n0   = (swz >> 6) * 256;            // 6 N-tiles

    const int wm   = (wv >> 2) * 128;             // 2 M-halves
    const int wn   = (wv & 3) * 64;               // 4 N-quarters
    const int lr   = ln & 15;
    const int lg   = ln >> 4;
    const int srow = ln & 15;                     // staging row within subtile
    const int schk = (ln >> 4) * 8;               // staging elem offset

    float4_t acc[8][4];
    #pragma unroll
    for (int m = 0; m < 8; ++m)
        #pragma unroll
        for (int n = 0; n < 4; ++n)
            acc[m][n] = (float4_t){0.f, 0.f, 0.f, 0.f};

    // stage K-tile kt into buffer base (A: 16 subtiles @0, B: 16 subtiles @8192)
    #define STAGE(kt_, base_) do {                                            \
        const int k0_ = (kt_) * BKQ;                                          \
        _Pragma("unroll")                                                     \
        for (int i_ = 0; i_ < 2; ++i_) {                                      \
            int s_ = i_ * 8 + wv;                                             \
            gload_lds16(Xb + (size_t)(m0 + s_ * 16 + srow) * KDIM + k0_ + schk,\
                        (base_) + s_ * 512);                                  \
        }                                                                     \
        _Pragma("unroll")                                                     \
        for (int i_ = 0; i_ < 2; ++i_) {                                      \
            int s_ = i_ * 8 + wv;                                             \
            gload_lds16(W + (size_t)(n0 + s_ * 16 + srow) * KDIM + k0_ + schk, \
                        (base_) + 8192 + s_ * 512);                           \
        }                                                                     \
    } while (0)

    // compute one K-tile from buffer base: 12 ds_read_b128, 2 phases x 16 MFMA
    #define COMPUTE(base_) do {                                               \
        const unsigned short* Ab_ = (base_);                                  \
        const unsigned short* Bb_ = (base_) + 8192;                           \
        short8 bf_[4];                                                        \
        _Pragma("unroll")                                                     \
        for (int n_ = 0; n_ < 4; ++n_)                                        \
            bf_[n_] = *reinterpret_cast<const short8*>(                       \
                &Bb_[((wn >> 4) + n_) * 512 + lg * 128 + lr * 8]);            \
        _Pragma("unroll")                                                     \
        for (int qm_ = 0; qm_ < 2; ++qm_) {                                   \
            short8 af_[4];                                                    \
            _Pragma("unroll")                                                 \
            for (int m_ = 0; m_ < 4; ++m_)                                    \
                af_[m_] = *reinterpret_cast<const short8*>(                   \
                    &Ab_[((wm >> 4) + qm_ * 4 + m_) * 512 + lg * 128 + lr * 8]);\
            __builtin_amdgcn_s_setprio(1);                                    \
            _Pragma("unroll")                                                 \
            for (int m_ = 0; m_ < 4; ++m_)                                    \
                _Pragma("unroll")                                             \
                for (int n_ = 0; n_ < 4; ++n_)                                \
                    acc[qm_ * 4 + m_][n_] =                                   \
                        __builtin_amdgcn_mfma_f32_16x16x32_bf16(              \
                            af_[m_], bf_[n_], acc[qm_ * 4 + m_][n_], 0, 0, 0);\
            __builtin_amdgcn_s_setprio(0);                                    \
        }                                                                     \
    } while (0)

    unsigned short* bc = lds;              // buffer for tile t
    unsigned short* b1 = lds + 16384;      // tile t+1
    unsigned short* b2 = lds + 32768;      // tile t+2 (free)

    STAGE(0, bc);
    STAGE(1, b1);                          // 8 loads outstanding

    for (int t = 0; t < 15; ++t) {
        asm volatile("s_waitcnt vmcnt(4)" ::: "memory");  // tile t landed; t+1 in flight
        __builtin_amdgcn_s_barrier();                     // publish; also WAR gate for b2
        __builtin_amdgcn_sched_barrier(0);
        if (t < 14) STAGE(t + 2, b2);                     // issue early (max cover)
        COMPUTE(bc);
        unsigned short* tmp = bc; bc = b1; b1 = b2; b2 = tmp;
    }
    asm volatile("s_waitcnt vmcnt(0)" ::: "memory");      // drain tile 15
    __builtin_amdgcn_s_barrier();
    __builtin_amdgcn_sched_barrier(0);
    COMPUTE(bc);
    #undef STAGE
    #undef COMPUTE

    // epilogue: bias, q-scale, scatter to (3,B,H,L,Dh) bf16
    const float qscale = 0.17677669529663687f;  // Dh^-0.5
    #pragma unroll
    for (int mf = 0; mf < 8; ++mf) {
        #pragma unroll
        for (int nf = 0; nf < 4; ++nf) {
            int gn    = n0 + wn + nf * 16 + lr;
            int which = gn >> 9;            // 0=q 1=k 2=v
            int hh    = (gn >> 5) & 15;
            int dd    = gn & 31;
            float bsv = bias[gn];
            #pragma unroll
            for (int r = 0; r < 4; ++r) {
                int gm = m0 + wm + mf * 16 + lg * 4 + r;
                float v = acc[mf][nf][r] + bsv;
                if (which == 0) v *= qscale;
                int b_ = gm >> 12, l = gm & 4095;
                size_t off = (((size_t)which * BATCH + b_) * HNUM + hh) *
                                 ((size_t)LSEQ * DH) + (size_t)l * DH + dd;
                qkvout[off] = f32_to_bf16(v);
            }
        }
    }
}

// ---------------------------------------------------------------- attention
// one block = (b, h, 256 consecutive l). K/V window staged in LDS as
// [cq][row][8] planes (16B row stride): lane-consecutive rows hit all 32 banks.
__global__ __launch_bounds__(256) void natten_fwd(
    const unsigned short* __restrict__ qkv,  // (3,B,H,L,Dh) bf16
    const float* __restrict__ rpb,           // (16,25) f32
    unsigned short* __restrict__ ctx)        // (B,L,C) bf16
{
    __shared__ __align__(16) unsigned short ks[4 * 268 * 8];
    __shared__ __align__(16) unsigned short vs[4 * 268 * 8];
    __shared__ float rpb_s[2 * KSZ - 1];

    const int t    = threadIdx.x;
    const int lblk = blockIdx.x & 15;       // L/256 = 16 chunks
    const int bh   = blockIdx.x >> 4;
    const int hh   = bh & 15, b_ = bh >> 4;
    const int l0   = lblk * 256;

    const int r0    = max(l0 - NHALF, 0);
    const int rend  = min(l0 + 256 + NHALF, LSEQ);
    const int nrows = rend - r0;            // <= 268

    const size_t plane = (size_t)LSEQ * DH;
    const size_t kbase = (((size_t)1 * BATCH + b_) * HNUM + hh) * plane;
    const size_t vbase = (((size_t)2 * BATCH + b_) * HNUM + hh) * plane;

    {
        const int cq  = t >> 6;
        const int rr  = t & 63;
        #pragma unroll
        for (int base = 0; base < 320; base += 64) {
            int row = base + rr;
            if (row < nrows) {
                *reinterpret_cast<short8*>(&ks[(cq * 268 + row) * 8]) =
                    *reinterpret_cast<const short8*>(&qkv[kbase + (size_t)(r0 + row) * DH + cq * 8]);
                *reinterpret_cast<short8*>(&vs[(cq * 268 + row) * 8]) =
                    *reinterpret_cast<const short8*>(&qkv[vbase + (size_t)(r0 + row) * DH + cq * 8]);
            }
        }
    }
    if (t < 2 * KSZ - 1) rpb_s[t] = rpb[hh * (2 * KSZ - 1) + t];
    __syncthreads();

    const int l = l0 + t;
    float q[DH];
    const size_t qoff = (((size_t)0 * BATCH + b_) * HNUM + hh) * plane + (size_t)l * DH;
    #pragma unroll
    for (int cq = 0; cq < 4; ++cq) {
        short8 qv = *reinterpret_cast<const short8*>(&qkv[qoff + cq * 8]);
        #pragma unroll
        for (int e = 0; e < 8; ++e) q[cq * 8 + e] = bf16_to_f32((unsigned short)qv[e]);
    }

    const int start = min(max(l - NHALF, 0), LSEQ - KSZ);
    float logit[KSZ];
    #pragma unroll
    for (int j = 0; j < KSZ; ++j) {
        int kr = start + j - r0;
        float s = 0.f;
        #pragma unroll
        for (int cq = 0; cq < 4; ++cq) {
            short8 kv = *reinterpret_cast<const short8*>(&ks[(cq * 268 + kr) * 8]);
            #pragma unroll
            for (int e = 0; e < 8; ++e)
                s += q[cq * 8 + e] * bf16_to_f32((unsigned short)kv[e]);
        }
        logit[j] = s + rpb_s[start + j - l + (KSZ - 1)];
    }
    float mx = logit[0];
    #pragma unroll
    for (int j = 1; j < KSZ; ++j) mx = fmaxf(mx, logit[j]);
    float p[KSZ], sum = 0.f;
    #pragma unroll
    for (int j = 0; j < KSZ; ++j) { p[j] = __expf(logit[j] - mx); sum += p[j]; }
    const float inv = 1.f / sum;

    float o[DH];
    #pragma unroll
    for (int d = 0; d < DH; ++d) o[d] = 0.f;
    #pragma unroll
    for (int j = 0; j < KSZ; ++j) {
        int kr = start + j - r0;
        float pj = p[j] * inv;
        #pragma unroll
        for (int cq = 0; cq < 4; ++cq) {
            short8 vv = *reinterpret_cast<const short8*>(&vs[(cq * 268 + kr) * 8]);
            #pragma unroll
            for (int e = 0; e < 8; ++e)
                o[cq * 8 + e] += pj * bf16_to_f32((unsigned short)vv[e]);
        }
    }
    const size_t obase = ((size_t)(b_ * LSEQ + l)) * CCH + hh * DH;
    #pragma unroll
    for (int cq = 0; cq < 4; ++cq) {
        short8 ov;
        #pragma unroll
        for (int e = 0; e < 8; ++e) ov[e] = (short)f32_to_bf16(o[cq * 8 + e]);
        *reinterpret_cast<short8*>(&ctx[obase + cq * 8]) = ov;
    }
}

// ---------------------------------------------------------------- GEMM 2: proj
// ctx (bf16, 16384x512) @ W^T (bf16 512x512) + bias -> out f32 (B,L,C)
// BM=256, BN=128, BK=32, 8 waves (4M x 2N, wave-tile 64x64), grid 256 (1/CU).
// Same subtiled-LDS triple-buffer counted-vmcnt pipeline (3 loads/tile).
__global__ __launch_bounds__(512, 1) void gemm_proj(
    const unsigned short* __restrict__ Xb,
    const unsigned short* __restrict__ W,
    const float* __restrict__ bias,
    float* __restrict__ out)
{
    extern __shared__ __align__(16) unsigned short lds[];  // 3 * 24KB
    const int tid  = threadIdx.x;
    const int wv   = tid >> 6, ln = tid & 63;

    const int wg   = blockIdx.x;
    const int swz  = (wg & 7) * 32 + (wg >> 3);   // bijective (256 = 8*32)
    const int m0   = (swz & 63) * 256;            // 64 M-tiles
    const int n0   = (swz >> 6) * 128;            // 4 N-tiles

    const int wm   = (wv >> 1) * 64;              // 4 M-quarters
    const int wn   = (wv & 1) * 64;               // 2 N-halves
    const int lr   = ln & 15;
    const int lg   = ln >> 4;
    const int srow = ln & 15;
    const int schk = (ln >> 4) * 8;

    float4_t acc[4][4];
    #pragma unroll
    for (int m = 0; m < 4; ++m)
        #pragma unroll
        for (int n = 0; n < 4; ++n)
            acc[m][n] = (float4_t){0.f, 0.f, 0.f, 0.f};

    #define STAGEP(kt_, base_) do {                                           \
        const int k0_ = (kt_) * BKQ;                                          \
        _Pragma("unroll")                                                     \
        for (int i_ = 0; i_ < 2; ++i_) {                                      \
            int s_ = i_ * 8 + wv;                                             \
            gload_lds16(Xb + (size_t)(m0 + s_ * 16 + srow) * KDIM + k0_ + schk,\
                        (base_) + s_ * 512);                                  \
        }                                                                     \
        gload_lds16(W + (size_t)(n0 + wv * 16 + srow) * KDIM + k0_ + schk,    \
                    (base_) + 8192 + wv * 512);                               \
    } while (0)

    #define COMPUTEP(base_) do {                                              \
        const unsigned short* Ab_ = (base_);                                  \
        const unsigned short* Bb_ = (base_) + 8192;                           \
        short8 af_[4], bf_[4];                                                \
        _Pragma("unroll")                                                     \
        for (int n_ = 0; n_ < 4; ++n_)                                        \
            bf_[n_] = *reinterpret_cast<const short8*>(                       \
                &Bb_[((wn >> 4) + n_) * 512 + lg * 128 + lr * 8]);            \
        _Pragma("unroll")                                                     \
        for (int m_ = 0; m_ < 4; ++m_)                                        \
            af_[m_] = *reinterpret_cast<const short8*>(                       \
                &Ab_[((wm >> 4) + m_) * 512 + lg * 128 + lr * 8]);            \
        __builtin_amdgcn_s_setprio(1);                                        \
        _Pragma("unroll")                                                     \
        for (int m_ = 0; m_ < 4; ++m_)                                        \
            _Pragma("unroll")                                                 \
            for (int n_ = 0; n_ < 4; ++n_)                                    \
                acc[m_][n_] = __builtin_amdgcn_mfma_f32_16x16x32_bf16(        \
                    af_[m_], bf_[n_], acc[m_][n_], 0, 0, 0);                  \
        __builtin_amdgcn_s_setprio(0);                                        \
    } while (0)

    unsigned short* bc = lds;
    unsigned short* b1 = lds + 12288;
    unsigned short* b2 = lds + 24576;

    STAGEP(0, bc);
    STAGEP(1, b1);                         // 6 loads outstanding

    for (int t = 0; t < 15; ++t) {
        asm volatile("s_waitcnt vmcnt(3)" ::: "memory");
        __builtin_amdgcn_s_barrier();
        __builtin_amdgcn_sched_barrier(0);
        if (t < 14) STAGEP(t + 2, b2);
        COMPUTEP(bc);
        unsigned short* tmp = bc; bc = b1; b1 = b2; b2 = tmp;
    }
    asm volatile("s_waitcnt vmcnt(0)" ::: "memory");
    __builtin_amdgcn_s_barrier();
    __builtin_amdgcn_sched_barrier(0);
    COMPUTEP(bc);
    #undef STAGEP
    #undef COMPUTEP

    #pragma unroll
    for (int mf = 0; mf < 4; ++mf) {
        #pragma unroll
        for (int nf = 0; nf < 4; ++nf) {
            int gn = n0 + wn + nf * 16 + lr;
            float bsv = bias[gn];
            #pragma unroll
            for (int r = 0; r < 4; ++r) {
                int gm = m0 + wm + mf * 16 + lg * 4 + r;
                out[(size_t)gm * CCH + gn] = acc[mf][nf][r] + bsv;
            }
        }
    }
}

// ---------------------------------------------------------------- launch
extern "C" void kernel_launch(void* const* d_in, const int* in_sizes, int n_in,
                              void* d_out, int out_size, void* d_ws, size_t ws_size,
                              hipStream_t stream) {
    const float* x      = (const float*)d_in[0];
    const float* qkv_w  = (const float*)d_in[1];
    const float* qkv_b  = (const float*)d_in[2];
    const float* rpb    = (const float*)d_in[3];
    const float* proj_w = (const float*)d_in[4];
    const float* proj_b = (const float*)d_in[5];
    float* out = (float*)d_out;
    char* ws = (char*)d_ws;

    // ws layout (bytes):
    //   qkv bf16 (3*B*H*L*Dh = 25165824 elems)   @ 0          : 50331648
    //   xb/ctx overlay (8388608 elems bf16)      @ 50331648   : 16777216
    //   qkv_w bf16 (786432 elems)                @ 67108864   :  1572864
    //   proj_w bf16 (262144 elems)               @ 68681728   :   524288
    unsigned short* qkv = (unsigned short*)(ws);
    unsigned short* xb  = (unsigned short*)(ws + 50331648);
    unsigned short* ctx = (unsigned short*)(ws + 50331648);
    unsigned short* wq  = (unsigned short*)(ws + 67108864);
    unsigned short* wp  = (unsigned short*)(ws + 68681728);

    cvt_f32_bf16_v4<<<2048, 256, 0, stream>>>((const float4_t*)x, (short4_t*)xb, M_TOT * KDIM / 4);
    cvt_f32_bf16_v4<<<768, 256, 0, stream>>>((const float4_t*)qkv_w, (short4_t*)wq, 786432 / 4);
    cvt_f32_bf16_v4<<<256, 256, 0, stream>>>((const float4_t*)proj_w, (short4_t*)wp, 262144 / 4);

    // 256x256 tiles: 64 x 6 = 384 blocks, 512 threads, 96 KB dynamic LDS
    gemm_qkv<<<384, 512, 98304, stream>>>(xb, wq, qkv_b, qkv);

    natten_fwd<<<BATCH * HNUM * (LSEQ / 256), 256, 0, stream>>>(qkv, rpb, ctx);

    // 256x128 tiles: 64 x 4 = 256 blocks, 512 threads, 72 KB dynamic LDS
    gemm_proj<<<256, 512, 73728, stream>>>(ctx, wp, proj_b, out);
}

// Round 6
// 101.771 us; speedup vs baseline: 1.0088x; 1.0088x over previous
//
#include <hip/hip_runtime.h>
#include <hip/hip_bf16.h>

// Problem constants (B=4, L=4096, C=512, H=16, Dh=32, K=13)
#define BATCH   4
#define LSEQ    4096
#define CCH     512
#define HNUM    16
#define DH      32
#define KSZ     13
#define NHALF   6           // K/2
#define M_TOT   16384       // B*L
#define N_QKV   1536        // 3*C
#define KDIM    512         // C
#define BK      64          // GEMM K-step (128B rows, XOR-swizzle domain of 8 chunks)

typedef __attribute__((ext_vector_type(8))) short  short8;
typedef __attribute__((ext_vector_type(4))) short  short4_t;
typedef __attribute__((ext_vector_type(4))) float  float4_t;

__device__ __forceinline__ unsigned short f32_to_bf16(float f) {
    union { float f; unsigned int u; } un; un.f = f;
    unsigned int u = un.u;
    u += 0x7FFFu + ((u >> 16) & 1u);   // RNE (inputs are finite)
    return (unsigned short)(u >> 16);
}
__device__ __forceinline__ float bf16_to_f32(unsigned short h) {
    union { unsigned int u; float f; } un; un.u = ((unsigned int)h) << 16;
    return un.f;
}

// async global(16B/lane) -> LDS; lds base must be wave-uniform, HW adds lane*16
__device__ __forceinline__ void gload_lds16(const unsigned short* g, unsigned short* l) {
    __builtin_amdgcn_global_load_lds(
        (const __attribute__((address_space(1))) unsigned int*)g,
        (__attribute__((address_space(3))) unsigned int*)l,
        16, 0, 0);
}

// ---------------------------------------------------------------- cvt f32->bf16
// one launch converts x, qkv_w, proj_w (grid-stride over the 3 ranges)
__global__ void cvt_all(const float4_t* __restrict__ xin,  short4_t* __restrict__ xo,  int nx,
                        const float4_t* __restrict__ w1in, short4_t* __restrict__ w1o, int n1,
                        const float4_t* __restrict__ w2in, short4_t* __restrict__ w2o, int n2) {
    int i = blockIdx.x * blockDim.x + threadIdx.x;
    int stride = gridDim.x * blockDim.x;
    int ntot = nx + n1 + n2;
    for (; i < ntot; i += stride) {
        const float4_t* src; short4_t* dst; int j;
        if (i < nx)            { src = xin;  dst = xo;  j = i; }
        else if (i < nx + n1)  { src = w1in; dst = w1o; j = i - nx; }
        else                   { src = w2in; dst = w2o; j = i - nx - n1; }
        float4_t v = src[j];
        short4_t h;
        h.x = (short)f32_to_bf16(v.x);
        h.y = (short)f32_to_bf16(v.y);
        h.z = (short)f32_to_bf16(v.z);
        h.w = (short)f32_to_bf16(v.w);
        dst[j] = h;
    }
}

// ---------------------------------------------------------------- GEMM 1: QKV
// Xb (bf16, 16384x512) @ W^T (bf16 1536x512) + bias -> qkv bf16 (3,B,H,L,Dh)
// R3 skeleton (proven: 0 conflicts, 31MB fetch): 128x128 block, BK=64,
// single-buffer 2-barrier loop, 8x128B-coalesced gload_lds staging with XOR
// chunk swizzle (slot c holds global chunk c^(row&7); reads apply same XOR).
// CHANGE vs R3: 2 waves (128 thr), wave-tile 64x128 -> 24 ds_read_b128 per
// 64 MFMA per K-iter (was 16 per 32) = 1.33x less LDS traffic per FLOP;
// LDS-throughput was the measured ceiling (MfmaUtil 25% == LDS busy ratio).
__global__ __launch_bounds__(128) void gemm_qkv(
    const unsigned short* __restrict__ Xb,
    const unsigned short* __restrict__ W,
    const float* __restrict__ bias,
    unsigned short* __restrict__ qkvout)
{
    __shared__ __align__(16) unsigned short As[128 * BK];
    __shared__ __align__(16) unsigned short Bs[128 * BK];
    const int tid  = threadIdx.x;
    const int wv   = tid >> 6, ln = tid & 63;
    const int m0   = blockIdx.x * 128;
    const int n0   = blockIdx.y * 128;
    const int wrow = wv * 64;                 // wave's 64-row half
    const int lr   = ln & 15;                 // fragment row/col
    const int lg   = ln >> 4;                 // k-group (0..3)
    const int rgrp = ln >> 3;                 // staging: row within 8-row chunk
    const int csw  = ((ln & 7) ^ rgrp) * 8;   // staging: swizzled source chunk

    float4_t acc[4][8];
    #pragma unroll
    for (int m = 0; m < 4; ++m)
        #pragma unroll
        for (int n = 0; n < 8; ++n)
            acc[m][n] = (float4_t){0.f, 0.f, 0.f, 0.f};

    for (int k0 = 0; k0 < KDIM; k0 += BK) {
        // stage A+B tiles (16 KB each): 16 chunks of 8 rows x 128B, 8 per wave
        #pragma unroll
        for (int it = 0; it < 8; ++it) {
            int ch  = it * 2 + wv;                // 0..15, wave-uniform
            int row = ch * 8 + rgrp;
            gload_lds16(Xb + (size_t)(m0 + row) * KDIM + k0 + csw,
                        &As[ch * 8 * BK]);
            gload_lds16(W  + (size_t)(n0 + row) * KDIM + k0 + csw,
                        &Bs[ch * 8 * BK]);
        }
        __syncthreads();
        short8 af[2][4], bfr[2][8];
        #pragma unroll
        for (int kk = 0; kk < 2; ++kk) {
            #pragma unroll
            for (int m = 0; m < 4; ++m) {
                int row = wrow + m * 16 + lr;
                int c   = (kk * 4 + lg) ^ (lr & 7);
                af[kk][m] = *reinterpret_cast<const short8*>(&As[row * BK + c * 8]);
            }
            #pragma unroll
            for (int n = 0; n < 8; ++n) {
                int row = n * 16 + lr;
                int c   = (kk * 4 + lg) ^ (lr & 7);
                bfr[kk][n] = *reinterpret_cast<const short8*>(&Bs[row * BK + c * 8]);
            }
        }
        #pragma unroll
        for (int kk = 0; kk < 2; ++kk)
            #pragma unroll
            for (int m = 0; m < 4; ++m)
                #pragma unroll
                for (int n = 0; n < 8; ++n)
                    acc[m][n] = __builtin_amdgcn_mfma_f32_16x16x32_bf16(
                        af[kk][m], bfr[kk][n], acc[m][n], 0, 0, 0);
        __syncthreads();
    }

    // epilogue: bias, q-scale, scatter to (3,B,H,L,Dh) bf16
    const float qscale = 0.17677669529663687f;  // Dh^-0.5
    #pragma unroll
    for (int mf = 0; mf < 4; ++mf) {
        #pragma unroll
        for (int nf = 0; nf < 8; ++nf) {
            int gn    = n0 + nf * 16 + lr;
            int which = gn >> 9;            // 0=q 1=k 2=v
            int hh    = (gn >> 5) & 15;
            int dd    = gn & 31;
            float bsv = bias[gn];
            #pragma unroll
            for (int r = 0; r < 4; ++r) {
                int gm = m0 + wrow + mf * 16 + lg * 4 + r;
                float v = acc[mf][nf][r] + bsv;
                if (which == 0) v *= qscale;
                int b_ = gm >> 12, l = gm & 4095;
                size_t off = (((size_t)which * BATCH + b_) * HNUM + hh) *
                                 ((size_t)LSEQ * DH) + (size_t)l * DH + dd;
                qkvout[off] = f32_to_bf16(v);
            }
        }
    }
}

// ---------------------------------------------------------------- attention
// one block = (b, h, 256 consecutive l). K/V window staged in LDS as
// [cq][row][8] planes (16B row stride): lane-consecutive rows hit all 32 banks.
__global__ __launch_bounds__(256) void natten_fwd(
    const unsigned short* __restrict__ qkv,  // (3,B,H,L,Dh) bf16
    const float* __restrict__ rpb,           // (16,25) f32
    unsigned short* __restrict__ ctx)        // (B,L,C) bf16
{
    __shared__ __align__(16) unsigned short ks[4 * 268 * 8];
    __shared__ __align__(16) unsigned short vs[4 * 268 * 8];
    __shared__ float rpb_s[2 * KSZ - 1];

    const int t    = threadIdx.x;
    const int lblk = blockIdx.x & 15;       // L/256 = 16 chunks
    const int bh   = blockIdx.x >> 4;
    const int hh   = bh & 15, b_ = bh >> 4;
    const int l0   = lblk * 256;

    const int r0    = max(l0 - NHALF, 0);
    const int rend  = min(l0 + 256 + NHALF, LSEQ);
    const int nrows = rend - r0;            // <= 268

    const size_t plane = (size_t)LSEQ * DH;
    const size_t kbase = (((size_t)1 * BATCH + b_) * HNUM + hh) * plane;
    const size_t vbase = (((size_t)2 * BATCH + b_) * HNUM + hh) * plane;

    {
        const int cq  = t >> 6;
        const int rr  = t & 63;
        #pragma unroll
        for (int base = 0; base < 320; base += 64) {
            int row = base + rr;
            if (row < nrows) {
                *reinterpret_cast<short8*>(&ks[(cq * 268 + row) * 8]) =
                    *reinterpret_cast<const short8*>(&qkv[kbase + (size_t)(r0 + row) * DH + cq * 8]);
                *reinterpret_cast<short8*>(&vs[(cq * 268 + row) * 8]) =
                    *reinterpret_cast<const short8*>(&qkv[vbase + (size_t)(r0 + row) * DH + cq * 8]);
            }
        }
    }
    if (t < 2 * KSZ - 1) rpb_s[t] = rpb[hh * (2 * KSZ - 1) + t];
    __syncthreads();

    const int l = l0 + t;
    float q[DH];
    const size_t qoff = (((size_t)0 * BATCH + b_) * HNUM + hh) * plane + (size_t)l * DH;
    #pragma unroll
    for (int cq = 0; cq < 4; ++cq) {
        short8 qv = *reinterpret_cast<const short8*>(&qkv[qoff + cq * 8]);
        #pragma unroll
        for (int e = 0; e < 8; ++e) q[cq * 8 + e] = bf16_to_f32((unsigned short)qv[e]);
    }

    const int start = min(max(l - NHALF, 0), LSEQ - KSZ);
    float logit[KSZ];
    #pragma unroll
    for (int j = 0; j < KSZ; ++j) {
        int kr = start + j - r0;
        float s = 0.f;
        #pragma unroll
        for (int cq = 0; cq < 4; ++cq) {
            short8 kv = *reinterpret_cast<const short8*>(&ks[(cq * 268 + kr) * 8]);
            #pragma unroll
            for (int e = 0; e < 8; ++e)
                s += q[cq * 8 + e] * bf16_to_f32((unsigned short)kv[e]);
        }
        logit[j] = s + rpb_s[start + j - l + (KSZ - 1)];
    }
    float mx = logit[0];
    #pragma unroll
    for (int j = 1; j < KSZ; ++j) mx = fmaxf(mx, logit[j]);
    float p[KSZ], sum = 0.f;
    #pragma unroll
    for (int j = 0; j < KSZ; ++j) { p[j] = __expf(logit[j] - mx); sum += p[j]; }
    const float inv = 1.f / sum;

    float o[DH];
    #pragma unroll
    for (int d = 0; d < DH; ++d) o[d] = 0.f;
    #pragma unroll
    for (int j = 0; j < KSZ; ++j) {
        int kr = start + j - r0;
        float pj = p[j] * inv;
        #pragma unroll
        for (int cq = 0; cq < 4; ++cq) {
            short8 vv = *reinterpret_cast<const short8*>(&vs[(cq * 268 + kr) * 8]);
            #pragma unroll
            for (int e = 0; e < 8; ++e)
                o[cq * 8 + e] += pj * bf16_to_f32((unsigned short)vv[e]);
        }
    }
    const size_t obase = ((size_t)(b_ * LSEQ + l)) * CCH + hh * DH;
    #pragma unroll
    for (int cq = 0; cq < 4; ++cq) {
        short8 ov;
        #pragma unroll
        for (int e = 0; e < 8; ++e) ov[e] = (short)f32_to_bf16(o[cq * 8 + e]);
        *reinterpret_cast<short8*>(&ctx[obase + cq * 8]) = ov;
    }
}

// ---------------------------------------------------------------- GEMM 2: proj
// ctx (bf16, 16384x512) @ W^T (bf16 512x512) + bias -> out f32 (B,L,C)
// Same structure as gemm_qkv (2 waves, wave-tile 64x128).
__global__ __launch_bounds__(128) void gemm_proj(
    const unsigned short* __restrict__ Xb,
    const unsigned short* __restrict__ W,
    const float* __restrict__ bias,
    float* __restrict__ out)
{
    __shared__ __align__(16) unsigned short As[128 * BK];
    __shared__ __align__(16) unsigned short Bs[128 * BK];
    const int tid  = threadIdx.x;
    const int wv   = tid >> 6, ln = tid & 63;
    const int m0   = blockIdx.x * 128;
    const int n0   = blockIdx.y * 128;
    const int wrow = wv * 64;
    const int lr   = ln & 15;
    const int lg   = ln >> 4;
    const int rgrp = ln >> 3;
    const int csw  = ((ln & 7) ^ rgrp) * 8;

    float4_t acc[4][8];
    #pragma unroll
    for (int m = 0; m < 4; ++m)
        #pragma unroll
        for (int n = 0; n < 8; ++n)
            acc[m][n] = (float4_t){0.f, 0.f, 0.f, 0.f};

    for (int k0 = 0; k0 < KDIM; k0 += BK) {
        #pragma unroll
        for (int it = 0; it < 8; ++it) {
            int ch  = it * 2 + wv;
            int row = ch * 8 + rgrp;
            gload_lds16(Xb + (size_t)(m0 + row) * KDIM + k0 + csw,
                        &As[ch * 8 * BK]);
            gload_lds16(W  + (size_t)(n0 + row) * KDIM + k0 + csw,
                        &Bs[ch * 8 * BK]);
        }
        __syncthreads();
        short8 af[2][4], bfr[2][8];
        #pragma unroll
        for (int kk = 0; kk < 2; ++kk) {
            #pragma unroll
            for (int m = 0; m < 4; ++m) {
                int row = wrow + m * 16 + lr;
                int c   = (kk * 4 + lg) ^ (lr & 7);
                af[kk][m] = *reinterpret_cast<const short8*>(&As[row * BK + c * 8]);
            }
            #pragma unroll
            for (int n = 0; n < 8; ++n) {
                int row = n * 16 + lr;
                int c   = (kk * 4 + lg) ^ (lr & 7);
                bfr[kk][n] = *reinterpret_cast<const short8*>(&Bs[row * BK + c * 8]);
            }
        }
        #pragma unroll
        for (int kk = 0; kk < 2; ++kk)
            #pragma unroll
            for (int m = 0; m < 4; ++m)
                #pragma unroll
                for (int n = 0; n < 8; ++n)
                    acc[m][n] = __builtin_amdgcn_mfma_f32_16x16x32_bf16(
                        af[kk][m], bfr[kk][n], acc[m][n], 0, 0, 0);
        __syncthreads();
    }

    #pragma unroll
    for (int mf = 0; mf < 4; ++mf) {
        #pragma unroll
        for (int nf = 0; nf < 8; ++nf) {
            int gn = n0 + nf * 16 + lr;
            float bsv = bias[gn];
            #pragma unroll
            for (int r = 0; r < 4; ++r) {
                int gm = m0 + wrow + mf * 16 + lg * 4 + r;
                out[(size_t)gm * CCH + gn] = acc[mf][nf][r] + bsv;
            }
        }
    }
}

// ---------------------------------------------------------------- launch
extern "C" void kernel_launch(void* const* d_in, const int* in_sizes, int n_in,
                              void* d_out, int out_size, void* d_ws, size_t ws_size,
                              hipStream_t stream) {
    const float* x      = (const float*)d_in[0];
    const float* qkv_w  = (const float*)d_in[1];
    const float* qkv_b  = (const float*)d_in[2];
    const float* rpb    = (const float*)d_in[3];
    const float* proj_w = (const float*)d_in[4];
    const float* proj_b = (const float*)d_in[5];
    float* out = (float*)d_out;
    char* ws = (char*)d_ws;

    // ws layout (bytes):
    //   qkv bf16 (3*B*H*L*Dh = 25165824 elems)   @ 0          : 50331648
    //   xb/ctx overlay (8388608 elems bf16)      @ 50331648   : 16777216
    //   qkv_w bf16 (786432 elems)                @ 67108864   :  1572864
    //   proj_w bf16 (262144 elems)               @ 68681728   :   524288
    unsigned short* qkv = (unsigned short*)(ws);
    unsigned short* xb  = (unsigned short*)(ws + 50331648);
    unsigned short* ctx = (unsigned short*)(ws + 50331648);
    unsigned short* wq  = (unsigned short*)(ws + 67108864);
    unsigned short* wp  = (unsigned short*)(ws + 68681728);

    // all f32->bf16 conversions in one launch
    cvt_all<<<2048, 256, 0, stream>>>(
        (const float4_t*)x,      (short4_t*)xb, M_TOT * KDIM / 4,
        (const float4_t*)qkv_w,  (short4_t*)wq, 786432 / 4,
        (const float4_t*)proj_w, (short4_t*)wp, 262144 / 4);

    dim3 g1(M_TOT / 128, N_QKV / 128);   // 128 x 12 = 1536 blocks
    gemm_qkv<<<g1, 128, 0, stream>>>(xb, wq, qkv_b, qkv);

    natten_fwd<<<BATCH * HNUM * (LSEQ / 256), 256, 0, stream>>>(qkv, rpb, ctx);

    dim3 g2(M_TOT / 128, CCH / 128);     // 128 x 4 = 512 blocks
    gemm_proj<<<g2, 128, 0, stream>>>(ctx, wp, proj_b, out);
}

// Round 7
// 93.705 us; speedup vs baseline: 1.0956x; 1.0861x over previous
//
#include <hip/hip_runtime.h>
#include <hip/hip_bf16.h>

// Problem constants (B=4, L=4096, C=512, H=16, Dh=32, K=13)
#define BATCH   4
#define LSEQ    4096
#define CCH     512
#define HNUM    16
#define DH      32
#define KSZ     13
#define NHALF   6           // K/2
#define M_TOT   16384       // B*L
#define N_QKV   1536        // 3*C
#define KDIM    512         // C
#define BK      64          // GEMM K-step (128B rows, XOR-swizzle domain of 8 chunks)

typedef __attribute__((ext_vector_type(8))) short  short8;
typedef __attribute__((ext_vector_type(4))) short  short4_t;
typedef __attribute__((ext_vector_type(4))) float  float4_t;

__device__ __forceinline__ unsigned short f32_to_bf16(float f) {
    union { float f; unsigned int u; } un; un.f = f;
    unsigned int u = un.u;
    u += 0x7FFFu + ((u >> 16) & 1u);   // RNE (inputs are finite)
    return (unsigned short)(u >> 16);
}
__device__ __forceinline__ float bf16_to_f32(unsigned short h) {
    union { unsigned int u; float f; } un; un.u = ((unsigned int)h) << 16;
    return un.f;
}

// async global(16B/lane) -> LDS; lds base must be wave-uniform, HW adds lane*16
__device__ __forceinline__ void gload_lds16(const unsigned short* g, unsigned short* l) {
    __builtin_amdgcn_global_load_lds(
        (const __attribute__((address_space(1))) unsigned int*)g,
        (__attribute__((address_space(3))) unsigned int*)l,
        16, 0, 0);
}

// ---------------------------------------------------------------- cvt f32->bf16
// one launch converts x, qkv_w, proj_w (grid-stride over the 3 ranges)
__global__ void cvt_all(const float4_t* __restrict__ xin,  short4_t* __restrict__ xo,  int nx,
                        const float4_t* __restrict__ w1in, short4_t* __restrict__ w1o, int n1,
                        const float4_t* __restrict__ w2in, short4_t* __restrict__ w2o, int n2) {
    int i = blockIdx.x * blockDim.x + threadIdx.x;
    int stride = gridDim.x * blockDim.x;
    int ntot = nx + n1 + n2;
    for (; i < ntot; i += stride) {
        const float4_t* src; short4_t* dst; int j;
        if (i < nx)            { src = xin;  dst = xo;  j = i; }
        else if (i < nx + n1)  { src = w1in; dst = w1o; j = i - nx; }
        else                   { src = w2in; dst = w2o; j = i - nx - n1; }
        float4_t v = src[j];
        short4_t h;
        h.x = (short)f32_to_bf16(v.x);
        h.y = (short)f32_to_bf16(v.y);
        h.z = (short)f32_to_bf16(v.z);
        h.w = (short)f32_to_bf16(v.w);
        dst[j] = h;
    }
}

// ---------------------------------------------------------------- GEMM 1: QKV
// Xb (bf16, 16384x512) @ W^T (W bf16 1536x512) + bias -> qkv bf16 (3,B,H,L,Dh)
// R3 skeleton (best measured: 41us, 0 conflicts): 128x128 tile, BK=64, 4 waves,
// single-buffer 2-barrier loop, 8x128B-coalesced gload_lds with XOR chunk
// swizzle (slot c holds global chunk c^(row&7); reads apply the same XOR).
// NEW vs R3: chunked XCD swizzle -- each XCD owns 192 consecutive wgids so
// its W panels (B depends only on n0) stay resident in its private L2.
__global__ __launch_bounds__(256) void gemm_qkv(
    const unsigned short* __restrict__ Xb,
    const unsigned short* __restrict__ W,
    const float* __restrict__ bias,
    unsigned short* __restrict__ qkvout)
{
    __shared__ __align__(16) unsigned short As[128 * BK];
    __shared__ __align__(16) unsigned short Bs[128 * BK];
    const int tid  = threadIdx.x;
    const int wv   = tid >> 6, ln = tid & 63;

    // chunked XCD swizzle: blockIdx round-robins XCDs (wg&7); give XCD k the
    // contiguous wgid range [k*192,(k+1)*192) (1536 = 8*192, bijective)
    const int wg   = blockIdx.x;
    const int wgid = (wg & 7) * 192 + (wg >> 3);
    const int m0   = (wgid & 127) * 128;   // 128 M-tiles (fastest)
    const int n0   = (wgid >> 7) * 128;    // 12 N-tiles

    const int wm   = (wv >> 1) * 64;
    const int wn   = (wv & 1) * 64;
    const int lr   = ln & 15;          // fragment row/col
    const int lg   = ln >> 4;          // k-group (0..3)
    const int rgrp = ln >> 3;          // staging: row within 8-row chunk
    const int csw  = ((ln & 7) ^ rgrp) * 8;  // staging: swizzled source chunk

    float4_t acc[4][4];
    #pragma unroll
    for (int m = 0; m < 4; ++m)
        #pragma unroll
        for (int n = 0; n < 4; ++n)
            acc[m][n] = (float4_t){0.f, 0.f, 0.f, 0.f};

    for (int k0 = 0; k0 < KDIM; k0 += BK) {
        // stage A+B tiles (16 KB each): 16 chunks of 8 rows x 128B, 4 per wave
        #pragma unroll
        for (int it = 0; it < 4; ++it) {
            int ch  = it * 4 + wv;               // 0..15, wave-uniform
            int row = ch * 8 + rgrp;
            gload_lds16(Xb + (size_t)(m0 + row) * KDIM + k0 + csw,
                        &As[ch * 8 * BK]);
            gload_lds16(W  + (size_t)(n0 + row) * KDIM + k0 + csw,
                        &Bs[ch * 8 * BK]);
        }
        __syncthreads();
        short8 af[2][4], bfr[2][4];
        #pragma unroll
        for (int kk = 0; kk < 2; ++kk) {
            #pragma unroll
            for (int m = 0; m < 4; ++m) {
                int row = wm + m * 16 + lr;
                int c   = (kk * 4 + lg) ^ (row & 7);
                af[kk][m] = *reinterpret_cast<const short8*>(&As[row * BK + c * 8]);
            }
            #pragma unroll
            for (int n = 0; n < 4; ++n) {
                int row = wn + n * 16 + lr;
                int c   = (kk * 4 + lg) ^ (row & 7);
                bfr[kk][n] = *reinterpret_cast<const short8*>(&Bs[row * BK + c * 8]);
            }
        }
        #pragma unroll
        for (int kk = 0; kk < 2; ++kk)
            #pragma unroll
            for (int m = 0; m < 4; ++m)
                #pragma unroll
                for (int n = 0; n < 4; ++n)
                    acc[m][n] = __builtin_amdgcn_mfma_f32_16x16x32_bf16(
                        af[kk][m], bfr[kk][n], acc[m][n], 0, 0, 0);
        __syncthreads();
    }

    // epilogue: bias, q-scale, scatter to (3,B,H,L,Dh) bf16
    const float qscale = 0.17677669529663687f;  // Dh^-0.5
    #pragma unroll
    for (int m = 0; m < 4; ++m) {
        #pragma unroll
        for (int n = 0; n < 4; ++n) {
            int gn    = n0 + wn + n * 16 + lr;
            int which = gn >> 9;            // 0=q 1=k 2=v
            int hh    = (gn >> 5) & 15;
            int dd    = gn & 31;
            float bsv = bias[gn];
            #pragma unroll
            for (int r = 0; r < 4; ++r) {
                int gm = m0 + wm + m * 16 + lg * 4 + r;
                float v = acc[m][n][r] + bsv;
                if (which == 0) v *= qscale;
                int b_ = gm >> 12, l = gm & 4095;
                size_t off = (((size_t)which * BATCH + b_) * HNUM + hh) *
                                 ((size_t)LSEQ * DH) + (size_t)l * DH + dd;
                qkvout[off] = f32_to_bf16(v);
            }
        }
    }
}

// ---------------------------------------------------------------- attention
// one block = (b, h, 256 consecutive l). K/V window staged in LDS as
// [cq][row][8] planes (16B row stride): lane-consecutive rows hit all 32 banks.
__global__ __launch_bounds__(256) void natten_fwd(
    const unsigned short* __restrict__ qkv,  // (3,B,H,L,Dh) bf16
    const float* __restrict__ rpb,           // (16,25) f32
    unsigned short* __restrict__ ctx)        // (B,L,C) bf16
{
    __shared__ __align__(16) unsigned short ks[4 * 268 * 8];
    __shared__ __align__(16) unsigned short vs[4 * 268 * 8];
    __shared__ float rpb_s[2 * KSZ - 1];

    const int t    = threadIdx.x;
    const int lblk = blockIdx.x & 15;       // L/256 = 16 chunks
    const int bh   = blockIdx.x >> 4;
    const int hh   = bh & 15, b_ = bh >> 4;
    const int l0   = lblk * 256;

    const int r0    = max(l0 - NHALF, 0);
    const int rend  = min(l0 + 256 + NHALF, LSEQ);
    const int nrows = rend - r0;            // <= 268

    const size_t plane = (size_t)LSEQ * DH;
    const size_t kbase = (((size_t)1 * BATCH + b_) * HNUM + hh) * plane;
    const size_t vbase = (((size_t)2 * BATCH + b_) * HNUM + hh) * plane;

    {
        const int cq  = t >> 6;
        const int rr  = t & 63;
        #pragma unroll
        for (int base = 0; base < 320; base += 64) {
            int row = base + rr;
            if (row < nrows) {
                *reinterpret_cast<short8*>(&ks[(cq * 268 + row) * 8]) =
                    *reinterpret_cast<const short8*>(&qkv[kbase + (size_t)(r0 + row) * DH + cq * 8]);
                *reinterpret_cast<short8*>(&vs[(cq * 268 + row) * 8]) =
                    *reinterpret_cast<const short8*>(&qkv[vbase + (size_t)(r0 + row) * DH + cq * 8]);
            }
        }
    }
    if (t < 2 * KSZ - 1) rpb_s[t] = rpb[hh * (2 * KSZ - 1) + t];
    __syncthreads();

    const int l = l0 + t;
    float q[DH];
    const size_t qoff = (((size_t)0 * BATCH + b_) * HNUM + hh) * plane + (size_t)l * DH;
    #pragma unroll
    for (int cq = 0; cq < 4; ++cq) {
        short8 qv = *reinterpret_cast<const short8*>(&qkv[qoff + cq * 8]);
        #pragma unroll
        for (int e = 0; e < 8; ++e) q[cq * 8 + e] = bf16_to_f32((unsigned short)qv[e]);
    }

    const int start = min(max(l - NHALF, 0), LSEQ - KSZ);
    float logit[KSZ];
    #pragma unroll
    for (int j = 0; j < KSZ; ++j) {
        int kr = start + j - r0;
        float s = 0.f;
        #pragma unroll
        for (int cq = 0; cq < 4; ++cq) {
            short8 kv = *reinterpret_cast<const short8*>(&ks[(cq * 268 + kr) * 8]);
            #pragma unroll
            for (int e = 0; e < 8; ++e)
                s += q[cq * 8 + e] * bf16_to_f32((unsigned short)kv[e]);
        }
        logit[j] = s + rpb_s[start + j - l + (KSZ - 1)];
    }
    float mx = logit[0];
    #pragma unroll
    for (int j = 1; j < KSZ; ++j) mx = fmaxf(mx, logit[j]);
    float p[KSZ], sum = 0.f;
    #pragma unroll
    for (int j = 0; j < KSZ; ++j) { p[j] = __expf(logit[j] - mx); sum += p[j]; }
    const float inv = 1.f / sum;

    float o[DH];
    #pragma unroll
    for (int d = 0; d < DH; ++d) o[d] = 0.f;
    #pragma unroll
    for (int j = 0; j < KSZ; ++j) {
        int kr = start + j - r0;
        float pj = p[j] * inv;
        #pragma unroll
        for (int cq = 0; cq < 4; ++cq) {
            short8 vv = *reinterpret_cast<const short8*>(&vs[(cq * 268 + kr) * 8]);
            #pragma unroll
            for (int e = 0; e < 8; ++e)
                o[cq * 8 + e] += pj * bf16_to_f32((unsigned short)vv[e]);
        }
    }
    const size_t obase = ((size_t)(b_ * LSEQ + l)) * CCH + hh * DH;
    #pragma unroll
    for (int cq = 0; cq < 4; ++cq) {
        short8 ov;
        #pragma unroll
        for (int e = 0; e < 8; ++e) ov[e] = (short)f32_to_bf16(o[cq * 8 + e]);
        *reinterpret_cast<short8*>(&ctx[obase + cq * 8]) = ov;
    }
}

// ---------------------------------------------------------------- GEMM 2: proj
// ctx (bf16, 16384x512) @ W^T (W bf16 512x512) + bias -> out f32 (B,L,C)
// R3 skeleton + chunked XCD swizzle (512 = 8*64).
__global__ __launch_bounds__(256) void gemm_proj(
    const unsigned short* __restrict__ Xb,
    const unsigned short* __restrict__ W,
    const float* __restrict__ bias,
    float* __restrict__ out)
{
    __shared__ __align__(16) unsigned short As[128 * BK];
    __shared__ __align__(16) unsigned short Bs[128 * BK];
    const int tid  = threadIdx.x;
    const int wv   = tid >> 6, ln = tid & 63;

    const int wg   = blockIdx.x;
    const int wgid = (wg & 7) * 64 + (wg >> 3);   // bijective (512 = 8*64)
    const int m0   = (wgid & 127) * 128;
    const int n0   = (wgid >> 7) * 128;

    const int wm   = (wv >> 1) * 64;
    const int wn   = (wv & 1) * 64;
    const int lr   = ln & 15;
    const int lg   = ln >> 4;
    const int rgrp = ln >> 3;
    const int csw  = ((ln & 7) ^ rgrp) * 8;

    float4_t acc[4][4];
    #pragma unroll
    for (int m = 0; m < 4; ++m)
        #pragma unroll
        for (int n = 0; n < 4; ++n)
            acc[m][n] = (float4_t){0.f, 0.f, 0.f, 0.f};

    for (int k0 = 0; k0 < KDIM; k0 += BK) {
        #pragma unroll
        for (int it = 0; it < 4; ++it) {
            int ch  = it * 4 + wv;
            int row = ch * 8 + rgrp;
            gload_lds16(Xb + (size_t)(m0 + row) * KDIM + k0 + csw,
                        &As[ch * 8 * BK]);
            gload_lds16(W  + (size_t)(n0 + row) * KDIM + k0 + csw,
                        &Bs[ch * 8 * BK]);
        }
        __syncthreads();
        short8 af[2][4], bfr[2][4];
        #pragma unroll
        for (int kk = 0; kk < 2; ++kk) {
            #pragma unroll
            for (int m = 0; m < 4; ++m) {
                int row = wm + m * 16 + lr;
                int c   = (kk * 4 + lg) ^ (row & 7);
                af[kk][m] = *reinterpret_cast<const short8*>(&As[row * BK + c * 8]);
            }
            #pragma unroll
            for (int n = 0; n < 4; ++n) {
                int row = wn + n * 16 + lr;
                int c   = (kk * 4 + lg) ^ (row & 7);
                bfr[kk][n] = *reinterpret_cast<const short8*>(&Bs[row * BK + c * 8]);
            }
        }
        #pragma unroll
        for (int kk = 0; kk < 2; ++kk)
            #pragma unroll
            for (int m = 0; m < 4; ++m)
                #pragma unroll
                for (int n = 0; n < 4; ++n)
                    acc[m][n] = __builtin_amdgcn_mfma_f32_16x16x32_bf16(
                        af[kk][m], bfr[kk][n], acc[m][n], 0, 0, 0);
        __syncthreads();
    }

    #pragma unroll
    for (int m = 0; m < 4; ++m) {
        #pragma unroll
        for (int n = 0; n < 4; ++n) {
            int gn = n0 + wn + n * 16 + lr;
            float bsv = bias[gn];
            #pragma unroll
            for (int r = 0; r < 4; ++r) {
                int gm = m0 + wm + m * 16 + lg * 4 + r;
                out[(size_t)gm * CCH + gn] = acc[m][n][r] + bsv;
            }
        }
    }
}

// ---------------------------------------------------------------- launch
extern "C" void kernel_launch(void* const* d_in, const int* in_sizes, int n_in,
                              void* d_out, int out_size, void* d_ws, size_t ws_size,
                              hipStream_t stream) {
    const float* x      = (const float*)d_in[0];
    const float* qkv_w  = (const float*)d_in[1];
    const float* qkv_b  = (const float*)d_in[2];
    const float* rpb    = (const float*)d_in[3];
    const float* proj_w = (const float*)d_in[4];
    const float* proj_b = (const float*)d_in[5];
    float* out = (float*)d_out;
    char* ws = (char*)d_ws;

    // ws layout (bytes):
    //   qkv bf16 (3*B*H*L*Dh = 25165824 elems)   @ 0          : 50331648
    //   xb/ctx overlay (8388608 elems bf16)      @ 50331648   : 16777216
    //   qkv_w bf16 (786432 elems)                @ 67108864   :  1572864
    //   proj_w bf16 (262144 elems)               @ 68681728   :   524288
    unsigned short* qkv = (unsigned short*)(ws);
    unsigned short* xb  = (unsigned short*)(ws + 50331648);
    unsigned short* ctx = (unsigned short*)(ws + 50331648);
    unsigned short* wq  = (unsigned short*)(ws + 67108864);
    unsigned short* wp  = (unsigned short*)(ws + 68681728);

    // all f32->bf16 conversions in one launch
    cvt_all<<<2048, 256, 0, stream>>>(
        (const float4_t*)x,      (short4_t*)xb, M_TOT * KDIM / 4,
        (const float4_t*)qkv_w,  (short4_t*)wq, 786432 / 4,
        (const float4_t*)proj_w, (short4_t*)wp, 262144 / 4);

    gemm_qkv<<<1536, 256, 0, stream>>>(xb, wq, qkv_b, qkv);

    natten_fwd<<<BATCH * HNUM * (LSEQ / 256), 256, 0, stream>>>(qkv, rpb, ctx);

    gemm_proj<<<512, 256, 0, stream>>>(ctx, wp, proj_b, out);
}

// Round 8
// 79.417 us; speedup vs baseline: 1.2927x; 1.1799x over previous
//
#include <hip/hip_runtime.h>
#include <hip/hip_bf16.h>

// Problem constants (B=4, L=4096, C=512, H=16, Dh=32, K=13)
#define BATCH   4
#define LSEQ    4096
#define CCH     512
#define HNUM    16
#define DH      32
#define KSZ     13
#define NHALF   6           // K/2
#define M_TOT   16384       // B*L
#define N_QKV   1536        // 3*C
#define KDIM    512         // C
#define BK      64          // GEMM K-step (128B rows, XOR-swizzle domain of 8 chunks)

typedef __attribute__((ext_vector_type(8))) short  short8;
typedef __attribute__((ext_vector_type(4))) short  short4_t;
typedef __attribute__((ext_vector_type(4))) float  float4_t;

__device__ __forceinline__ unsigned short f32_to_bf16(float f) {
    union { float f; unsigned int u; } un; un.f = f;
    unsigned int u = un.u;
    u += 0x7FFFu + ((u >> 16) & 1u);   // RNE (inputs are finite)
    return (unsigned short)(u >> 16);
}
__device__ __forceinline__ float bf16_to_f32(unsigned short h) {
    union { unsigned int u; float f; } un; un.u = ((unsigned int)h) << 16;
    return un.f;
}

// async global(16B/lane) -> LDS; lds base must be wave-uniform, HW adds lane*16
__device__ __forceinline__ void gload_lds16(const unsigned short* g, unsigned short* l) {
    __builtin_amdgcn_global_load_lds(
        (const __attribute__((address_space(1))) unsigned int*)g,
        (__attribute__((address_space(3))) unsigned int*)l,
        16, 0, 0);
}

// ---------------------------------------------------------------- cvt f32->bf16
// one launch converts x, qkv_w, proj_w (grid-stride over the 3 ranges)
__global__ void cvt_all(const float4_t* __restrict__ xin,  short4_t* __restrict__ xo,  int nx,
                        const float4_t* __restrict__ w1in, short4_t* __restrict__ w1o, int n1,
                        const float4_t* __restrict__ w2in, short4_t* __restrict__ w2o, int n2) {
    int i = blockIdx.x * blockDim.x + threadIdx.x;
    int stride = gridDim.x * blockDim.x;
    int ntot = nx + n1 + n2;
    for (; i < ntot; i += stride) {
        const float4_t* src; short4_t* dst; int j;
        if (i < nx)            { src = xin;  dst = xo;  j = i; }
        else if (i < nx + n1)  { src = w1in; dst = w1o; j = i - nx; }
        else                   { src = w2in; dst = w2o; j = i - nx - n1; }
        float4_t v = src[j];
        short4_t h;
        h.x = (short)f32_to_bf16(v.x);
        h.y = (short)f32_to_bf16(v.y);
        h.z = (short)f32_to_bf16(v.z);
        h.w = (short)f32_to_bf16(v.w);
        dst[j] = h;
    }
}

// ---------------------------------------------------------------- GEMM 1: QKV
// Xb (bf16, 16384x512) @ W^T (W bf16 1536x512) + bias -> qkv bf16 (3,B,H,L,Dh)
// R3 skeleton (proven: 0 conflicts, 31MB fetch, plain 2D grid) + T3 2-phase
// pipeline: double-buffered BK=64 K-tiles, STAGE(t+1) issued at iter top,
// counted s_waitcnt vmcnt(8) (tile t's 8 loads; t+1's stay in flight), raw
// s_barrier (no vmcnt(0) drain in-loop). 64KB LDS -> 2 blocks/CU.
__global__ __launch_bounds__(256) void gemm_qkv(
    const unsigned short* __restrict__ Xb,
    const unsigned short* __restrict__ W,
    const float* __restrict__ bias,
    unsigned short* __restrict__ qkvout)
{
    extern __shared__ __align__(16) unsigned short lds[];  // 65536 B
    // shorts: A0 @0, B0 @8192, A1 @16384, B1 @24576 (each 128*64 = 8192)
    const int tid  = threadIdx.x;
    const int wv   = tid >> 6, ln = tid & 63;
    const int m0   = blockIdx.x * 128;
    const int n0   = blockIdx.y * 128;
    const int wm   = (wv >> 1) * 64;
    const int wn   = (wv & 1) * 64;
    const int lr   = ln & 15;          // fragment row/col
    const int lg   = ln >> 4;          // k-group (0..3)
    const int rgrp = ln >> 3;          // staging: row within 8-row chunk
    const int csw  = ((ln & 7) ^ rgrp) * 8;  // staging: swizzled source chunk

    float4_t acc[4][4];
    #pragma unroll
    for (int m = 0; m < 4; ++m)
        #pragma unroll
        for (int n = 0; n < 4; ++n)
            acc[m][n] = (float4_t){0.f, 0.f, 0.f, 0.f};

    // stage K-tile at k0_ into (abuf_, bbuf_): 4+4 gload_lds of 1KB per wave
    #define STAGE(k0_, abuf_, bbuf_) do {                                     \
        _Pragma("unroll")                                                     \
        for (int it_ = 0; it_ < 4; ++it_) {                                   \
            int ch_  = it_ * 4 + wv;             /* 0..15, wave-uniform */    \
            int row_ = ch_ * 8 + rgrp;                                        \
            gload_lds16(Xb + (size_t)(m0 + row_) * KDIM + (k0_) + csw,        \
                        (abuf_) + ch_ * 8 * BK);                              \
            gload_lds16(W  + (size_t)(n0 + row_) * KDIM + (k0_) + csw,        \
                        (bbuf_) + ch_ * 8 * BK);                              \
        }                                                                     \
    } while (0)

    unsigned short* Ac = lds;           unsigned short* Bc = lds + 8192;
    unsigned short* An = lds + 16384;   unsigned short* Bn = lds + 24576;

    STAGE(0, Ac, Bc);                  // prologue: 8 loads outstanding

    for (int t = 0; t < 8; ++t) {
        if (t < 7) {
            STAGE((t + 1) * BK, An, Bn);                      // 8 more in flight
            asm volatile("s_waitcnt vmcnt(8)" ::: "memory");  // tile t landed
        } else {
            asm volatile("s_waitcnt vmcnt(0)" ::: "memory");  // drain last tile
        }
        __builtin_amdgcn_s_barrier();                         // publish tile t

        short8 af[2][4], bfr[2][4];
        #pragma unroll
        for (int kk = 0; kk < 2; ++kk) {
            #pragma unroll
            for (int m = 0; m < 4; ++m) {
                int row = wm + m * 16 + lr;
                int c   = (kk * 4 + lg) ^ (row & 7);
                af[kk][m] = *reinterpret_cast<const short8*>(&Ac[row * BK + c * 8]);
            }
            #pragma unroll
            for (int n = 0; n < 4; ++n) {
                int row = wn + n * 16 + lr;
                int c   = (kk * 4 + lg) ^ (row & 7);
                bfr[kk][n] = *reinterpret_cast<const short8*>(&Bc[row * BK + c * 8]);
            }
        }
        #pragma unroll
        for (int kk = 0; kk < 2; ++kk)
            #pragma unroll
            for (int m = 0; m < 4; ++m)
                #pragma unroll
                for (int n = 0; n < 4; ++n)
                    acc[m][n] = __builtin_amdgcn_mfma_f32_16x16x32_bf16(
                        af[kk][m], bfr[kk][n], acc[m][n], 0, 0, 0);

        if (t < 7) __builtin_amdgcn_s_barrier();  // WAR gate: all reads of this
                                                  // buf done before t+1 refills it
        unsigned short* tA = Ac; Ac = An; An = tA;
        unsigned short* tB = Bc; Bc = Bn; Bn = tB;
    }
    #undef STAGE

    // epilogue: bias, q-scale, scatter to (3,B,H,L,Dh) bf16
    const float qscale = 0.17677669529663687f;  // Dh^-0.5
    #pragma unroll
    for (int m = 0; m < 4; ++m) {
        #pragma unroll
        for (int n = 0; n < 4; ++n) {
            int gn    = n0 + wn + n * 16 + lr;
            int which = gn >> 9;            // 0=q 1=k 2=v
            int hh    = (gn >> 5) & 15;
            int dd    = gn & 31;
            float bsv = bias[gn];
            #pragma unroll
            for (int r = 0; r < 4; ++r) {
                int gm = m0 + wm + m * 16 + lg * 4 + r;
                float v = acc[m][n][r] + bsv;
                if (which == 0) v *= qscale;
                int b_ = gm >> 12, l = gm & 4095;
                size_t off = (((size_t)which * BATCH + b_) * HNUM + hh) *
                                 ((size_t)LSEQ * DH) + (size_t)l * DH + dd;
                qkvout[off] = f32_to_bf16(v);
            }
        }
    }
}

// ---------------------------------------------------------------- attention
// one block = (b, h, 256 consecutive l). K/V window staged in LDS as
// [cq][row][8] planes (16B row stride): lane-consecutive rows hit all 32 banks.
__global__ __launch_bounds__(256) void natten_fwd(
    const unsigned short* __restrict__ qkv,  // (3,B,H,L,Dh) bf16
    const float* __restrict__ rpb,           // (16,25) f32
    unsigned short* __restrict__ ctx)        // (B,L,C) bf16
{
    __shared__ __align__(16) unsigned short ks[4 * 268 * 8];
    __shared__ __align__(16) unsigned short vs[4 * 268 * 8];
    __shared__ float rpb_s[2 * KSZ - 1];

    const int t    = threadIdx.x;
    const int lblk = blockIdx.x & 15;       // L/256 = 16 chunks
    const int bh   = blockIdx.x >> 4;
    const int hh   = bh & 15, b_ = bh >> 4;
    const int l0   = lblk * 256;

    const int r0    = max(l0 - NHALF, 0);
    const int rend  = min(l0 + 256 + NHALF, LSEQ);
    const int nrows = rend - r0;            // <= 268

    const size_t plane = (size_t)LSEQ * DH;
    const size_t kbase = (((size_t)1 * BATCH + b_) * HNUM + hh) * plane;
    const size_t vbase = (((size_t)2 * BATCH + b_) * HNUM + hh) * plane;

    {
        const int cq  = t >> 6;
        const int rr  = t & 63;
        #pragma unroll
        for (int base = 0; base < 320; base += 64) {
            int row = base + rr;
            if (row < nrows) {
                *reinterpret_cast<short8*>(&ks[(cq * 268 + row) * 8]) =
                    *reinterpret_cast<const short8*>(&qkv[kbase + (size_t)(r0 + row) * DH + cq * 8]);
                *reinterpret_cast<short8*>(&vs[(cq * 268 + row) * 8]) =
                    *reinterpret_cast<const short8*>(&qkv[vbase + (size_t)(r0 + row) * DH + cq * 8]);
            }
        }
    }
    if (t < 2 * KSZ - 1) rpb_s[t] = rpb[hh * (2 * KSZ - 1) + t];
    __syncthreads();

    const int l = l0 + t;
    float q[DH];
    const size_t qoff = (((size_t)0 * BATCH + b_) * HNUM + hh) * plane + (size_t)l * DH;
    #pragma unroll
    for (int cq = 0; cq < 4; ++cq) {
        short8 qv = *reinterpret_cast<const short8*>(&qkv[qoff + cq * 8]);
        #pragma unroll
        for (int e = 0; e < 8; ++e) q[cq * 8 + e] = bf16_to_f32((unsigned short)qv[e]);
    }

    const int start = min(max(l - NHALF, 0), LSEQ - KSZ);
    float logit[KSZ];
    #pragma unroll
    for (int j = 0; j < KSZ; ++j) {
        int kr = start + j - r0;
        float s = 0.f;
        #pragma unroll
        for (int cq = 0; cq < 4; ++cq) {
            short8 kv = *reinterpret_cast<const short8*>(&ks[(cq * 268 + kr) * 8]);
            #pragma unroll
            for (int e = 0; e < 8; ++e)
                s += q[cq * 8 + e] * bf16_to_f32((unsigned short)kv[e]);
        }
        logit[j] = s + rpb_s[start + j - l + (KSZ - 1)];
    }
    float mx = logit[0];
    #pragma unroll
    for (int j = 1; j < KSZ; ++j) mx = fmaxf(mx, logit[j]);
    float p[KSZ], sum = 0.f;
    #pragma unroll
    for (int j = 0; j < KSZ; ++j) { p[j] = __expf(logit[j] - mx); sum += p[j]; }
    const float inv = 1.f / sum;

    float o[DH];
    #pragma unroll
    for (int d = 0; d < DH; ++d) o[d] = 0.f;
    #pragma unroll
    for (int j = 0; j < KSZ; ++j) {
        int kr = start + j - r0;
        float pj = p[j] * inv;
        #pragma unroll
        for (int cq = 0; cq < 4; ++cq) {
            short8 vv = *reinterpret_cast<const short8*>(&vs[(cq * 268 + kr) * 8]);
            #pragma unroll
            for (int e = 0; e < 8; ++e)
                o[cq * 8 + e] += pj * bf16_to_f32((unsigned short)vv[e]);
        }
    }
    const size_t obase = ((size_t)(b_ * LSEQ + l)) * CCH + hh * DH;
    #pragma unroll
    for (int cq = 0; cq < 4; ++cq) {
        short8 ov;
        #pragma unroll
        for (int e = 0; e < 8; ++e) ov[e] = (short)f32_to_bf16(o[cq * 8 + e]);
        *reinterpret_cast<short8*>(&ctx[obase + cq * 8]) = ov;
    }
}

// ---------------------------------------------------------------- GEMM 2: proj
// ctx (bf16, 16384x512) @ W^T (W bf16 512x512) + bias -> out f32 (B,L,C)
// Same R3 skeleton + 2-phase dbuf pipeline. Grid 512 = exactly 2 blocks/CU.
__global__ __launch_bounds__(256) void gemm_proj(
    const unsigned short* __restrict__ Xb,
    const unsigned short* __restrict__ W,
    const float* __restrict__ bias,
    float* __restrict__ out)
{
    extern __shared__ __align__(16) unsigned short lds[];  // 65536 B
    const int tid  = threadIdx.x;
    const int wv   = tid >> 6, ln = tid & 63;
    const int m0   = blockIdx.x * 128;
    const int n0   = blockIdx.y * 128;
    const int wm   = (wv >> 1) * 64;
    const int wn   = (wv & 1) * 64;
    const int lr   = ln & 15;
    const int lg   = ln >> 4;
    const int rgrp = ln >> 3;
    const int csw  = ((ln & 7) ^ rgrp) * 8;

    float4_t acc[4][4];
    #pragma unroll
    for (int m = 0; m < 4; ++m)
        #pragma unroll
        for (int n = 0; n < 4; ++n)
            acc[m][n] = (float4_t){0.f, 0.f, 0.f, 0.f};

    #define STAGEP(k0_, abuf_, bbuf_) do {                                    \
        _Pragma("unroll")                                                     \
        for (int it_ = 0; it_ < 4; ++it_) {                                   \
            int ch_  = it_ * 4 + wv;                                          \
            int row_ = ch_ * 8 + rgrp;                                        \
            gload_lds16(Xb + (size_t)(m0 + row_) * KDIM + (k0_) + csw,        \
                        (abuf_) + ch_ * 8 * BK);                              \
            gload_lds16(W  + (size_t)(n0 + row_) * KDIM + (k0_) + csw,        \
                        (bbuf_) + ch_ * 8 * BK);                              \
        }                                                                     \
    } while (0)

    unsigned short* Ac = lds;           unsigned short* Bc = lds + 8192;
    unsigned short* An = lds + 16384;   unsigned short* Bn = lds + 24576;

    STAGEP(0, Ac, Bc);

    for (int t = 0; t < 8; ++t) {
        if (t < 7) {
            STAGEP((t + 1) * BK, An, Bn);
            asm volatile("s_waitcnt vmcnt(8)" ::: "memory");
        } else {
            asm volatile("s_waitcnt vmcnt(0)" ::: "memory");
        }
        __builtin_amdgcn_s_barrier();

        short8 af[2][4], bfr[2][4];
        #pragma unroll
        for (int kk = 0; kk < 2; ++kk) {
            #pragma unroll
            for (int m = 0; m < 4; ++m) {
                int row = wm + m * 16 + lr;
                int c   = (kk * 4 + lg) ^ (row & 7);
                af[kk][m] = *reinterpret_cast<const short8*>(&Ac[row * BK + c * 8]);
            }
            #pragma unroll
            for (int n = 0; n < 4; ++n) {
                int row = wn + n * 16 + lr;
                int c   = (kk * 4 + lg) ^ (row & 7);
                bfr[kk][n] = *reinterpret_cast<const short8*>(&Bc[row * BK + c * 8]);
            }
        }
        #pragma unroll
        for (int kk = 0; kk < 2; ++kk)
            #pragma unroll
            for (int m = 0; m < 4; ++m)
                #pragma unroll
                for (int n = 0; n < 4; ++n)
                    acc[m][n] = __builtin_amdgcn_mfma_f32_16x16x32_bf16(
                        af[kk][m], bfr[kk][n], acc[m][n], 0, 0, 0);

        if (t < 7) __builtin_amdgcn_s_barrier();
        unsigned short* tA = Ac; Ac = An; An = tA;
        unsigned short* tB = Bc; Bc = Bn; Bn = tB;
    }
    #undef STAGEP

    #pragma unroll
    for (int m = 0; m < 4; ++m) {
        #pragma unroll
        for (int n = 0; n < 4; ++n) {
            int gn = n0 + wn + n * 16 + lr;
            float bsv = bias[gn];
            #pragma unroll
            for (int r = 0; r < 4; ++r) {
                int gm = m0 + wm + m * 16 + lg * 4 + r;
                out[(size_t)gm * CCH + gn] = acc[m][n][r] + bsv;
            }
        }
    }
}

// ---------------------------------------------------------------- launch
extern "C" void kernel_launch(void* const* d_in, const int* in_sizes, int n_in,
                              void* d_out, int out_size, void* d_ws, size_t ws_size,
                              hipStream_t stream) {
    const float* x      = (const float*)d_in[0];
    const float* qkv_w  = (const float*)d_in[1];
    const float* qkv_b  = (const float*)d_in[2];
    const float* rpb    = (const float*)d_in[3];
    const float* proj_w = (const float*)d_in[4];
    const float* proj_b = (const float*)d_in[5];
    float* out = (float*)d_out;
    char* ws = (char*)d_ws;

    // ws layout (bytes):
    //   qkv bf16 (3*B*H*L*Dh = 25165824 elems)   @ 0          : 50331648
    //   xb/ctx overlay (8388608 elems bf16)      @ 50331648   : 16777216
    //   qkv_w bf16 (786432 elems)                @ 67108864   :  1572864
    //   proj_w bf16 (262144 elems)               @ 68681728   :   524288
    unsigned short* qkv = (unsigned short*)(ws);
    unsigned short* xb  = (unsigned short*)(ws + 50331648);
    unsigned short* ctx = (unsigned short*)(ws + 50331648);
    unsigned short* wq  = (unsigned short*)(ws + 67108864);
    unsigned short* wp  = (unsigned short*)(ws + 68681728);

    // all f32->bf16 conversions in one launch
    cvt_all<<<2048, 256, 0, stream>>>(
        (const float4_t*)x,      (short4_t*)xb, M_TOT * KDIM / 4,
        (const float4_t*)qkv_w,  (short4_t*)wq, 786432 / 4,
        (const float4_t*)proj_w, (short4_t*)wp, 262144 / 4);

    dim3 g1(M_TOT / 128, N_QKV / 128);   // 128 x 12 = 1536 blocks
    gemm_qkv<<<g1, 256, 65536, stream>>>(xb, wq, qkv_b, qkv);

    natten_fwd<<<BATCH * HNUM * (LSEQ / 256), 256, 0, stream>>>(qkv, rpb, ctx);

    dim3 g2(M_TOT / 128, CCH / 128);     // 128 x 4 = 512 blocks
    gemm_proj<<<g2, 256, 65536, stream>>>(ctx, wp, proj_b, out);
}